// Round 1
// 753.987 us; speedup vs baseline: 1.0473x; 1.0473x over previous
//
#include <hip/hip_runtime.h>
#include <math.h>

#define Bsz 4
#define Tseq 2048
#define Ed 1024
#define Hh 16
#define E3 (3*Ed)
#define MROWS (Bsz*Tseq)

typedef short short8 __attribute__((ext_vector_type(8)));
typedef _Float16 half8 __attribute__((ext_vector_type(8)));
typedef float floatx4 __attribute__((ext_vector_type(4)));

__device__ __forceinline__ unsigned short f2bf(float f) {
  unsigned int u = __builtin_bit_cast(unsigned int, f);
  u += 0x7fffu + ((u >> 16) & 1u);           // RNE (finite inputs)
  return (unsigned short)(u >> 16);
}
__device__ __forceinline__ float bf2f(unsigned short u) {
  return __builtin_bit_cast(float, ((unsigned int)u) << 16);
}
__device__ __forceinline__ unsigned short f2h(float f) {
  _Float16 h = (_Float16)f;
  return __builtin_bit_cast(unsigned short, h);
}
__device__ __forceinline__ float h2f(unsigned short u) {
  return (float)__builtin_bit_cast(_Float16, u);
}
// swizzled element index in a 64-col bf16 tile (group-of-8 XOR on row)
__device__ __forceinline__ int swz(int row, int col) {
  return row * 64 + ((((col >> 3) ^ (row & 7)) << 3) | (col & 7));
}

// ---------------- x -> bf16 + fp16 hi/lo split -------------------------------
__global__ __launch_bounds__(256)
void cast_split_k(const float* __restrict__ s, unsigned short* __restrict__ bb,
                  unsigned short* __restrict__ hh, unsigned short* __restrict__ ll,
                  int n4) {
  int i = blockIdx.x * 256 + threadIdx.x;
  if (i >= n4) return;
  float4 v = ((const float4*)s)[i];
  float vv[4] = {v.x, v.y, v.z, v.w};
  unsigned short ob[4], oh[4], ol[4];
  #pragma unroll
  for (int j = 0; j < 4; ++j) {
    ob[j] = f2bf(vv[j]);
    unsigned short h = f2h(vv[j]);
    oh[j] = h;
    ol[j] = f2h(vv[j] - h2f(h));
  }
  ((uint2*)bb)[i] = *(uint2*)ob;
  ((uint2*)hh)[i] = *(uint2*)oh;
  ((uint2*)ll)[i] = *(uint2*)ol;
}

// ---------------- fp32 [K][ld] (col window c0) -> bf16 [N][K] transpose -----
__global__ __launch_bounds__(256)
void transpose_cast(const float* __restrict__ src, int ld, int c0,
                    unsigned short* __restrict__ dst, int Krows) {
  __shared__ float t[64][65];
  const int kb = blockIdx.y * 64, nb = blockIdx.x * 64;
  const int tid = threadIdx.x;
  #pragma unroll
  for (int i = 0; i < 4; ++i) {
    int u = tid + i * 256;                 // 1024 float4 units
    int r = u >> 4, c4 = u & 15;
    float4 v = *(const float4*)(src + (size_t)(kb + r) * ld + c0 + nb + c4 * 4);
    t[r][c4*4+0] = v.x; t[r][c4*4+1] = v.y; t[r][c4*4+2] = v.z; t[r][c4*4+3] = v.w;
  }
  __syncthreads();
  #pragma unroll
  for (int i = 0; i < 2; ++i) {
    int u = tid + i * 256;                 // 512 units: 64 n-rows x 8 k-groups
    int rn = u >> 3, g = u & 7;
    unsigned short o[8];
    #pragma unroll
    for (int j = 0; j < 8; ++j) o[j] = f2bf(t[g*8+j][rn]);
    *(uint4*)(dst + (size_t)(nb + rn) * Krows + kb + g * 8) = *(uint4*)o;
  }
}

// ---------------- fp32 [K][ld] (col window c0) -> fp16 hi/lo [N][K] ---------
__global__ __launch_bounds__(256)
void transpose_split(const float* __restrict__ src, int ld, int c0,
                     unsigned short* __restrict__ dh, unsigned short* __restrict__ dl,
                     int Krows) {
  __shared__ float t[64][65];
  const int kb = blockIdx.y * 64, nb = blockIdx.x * 64;
  const int tid = threadIdx.x;
  #pragma unroll
  for (int i = 0; i < 4; ++i) {
    int u = tid + i * 256;
    int r = u >> 4, c4 = u & 15;
    float4 v = *(const float4*)(src + (size_t)(kb + r) * ld + c0 + nb + c4 * 4);
    t[r][c4*4+0] = v.x; t[r][c4*4+1] = v.y; t[r][c4*4+2] = v.z; t[r][c4*4+3] = v.w;
  }
  __syncthreads();
  #pragma unroll
  for (int i = 0; i < 2; ++i) {
    int u = tid + i * 256;
    int rn = u >> 3, g = u & 7;
    unsigned short oh[8], ol[8];
    #pragma unroll
    for (int j = 0; j < 8; ++j) {
      float f = t[g*8+j][rn];
      unsigned short h = f2h(f);
      oh[j] = h;
      ol[j] = f2h(f - h2f(h));
    }
    size_t off = (size_t)(nb + rn) * Krows + kb + g * 8;
    *(uint4*)(dh + off) = *(uint4*)oh;
    *(uint4*)(dl + off) = *(uint4*)ol;
  }
}

// ---------------- bf16 MFMA GEMM: C[M,N] = A[M,K] * Bt[N,K]^T ---------------
// 128x128 tile, BK=64, 4 waves (2x2), each wave 64x64 via 4x4 16x16x32 MFMAs.
template<int N, int KD, bool OBF>
__global__ __launch_bounds__(256)
void gemm_bf16(const unsigned short* __restrict__ A,
               const unsigned short* __restrict__ Bt,
               void* __restrict__ C) {
  __shared__ __align__(16) unsigned short As[128][72];  // [m][k], +8 pad
  __shared__ __align__(16) unsigned short Bs[128][72];  // [n][k], +8 pad
  const int tid = threadIdx.x;
  const int w = tid >> 6, L = tid & 63, Ln = L & 15, Lq = L >> 4;
  const int wm = w & 1, wn = w >> 1;
  const int m0 = blockIdx.y * 128, n0 = blockIdx.x * 128;

  floatx4 acc[4][4];
  #pragma unroll
  for (int mt = 0; mt < 4; ++mt)
    #pragma unroll
    for (int nt = 0; nt < 4; ++nt) acc[mt][nt] = (floatx4)0.f;

  for (int kt = 0; kt < KD; kt += 64) {
    #pragma unroll
    for (int i = 0; i < 4; ++i) {
      int u = tid + i * 256;               // 1024 uint4 units per operand
      int row = u >> 3, g = u & 7;
      *(uint4*)&As[row][g*8] = *(const uint4*)(A + (size_t)(m0 + row) * KD + kt + g * 8);
      *(uint4*)&Bs[row][g*8] = *(const uint4*)(Bt + (size_t)(n0 + row) * KD + kt + g * 8);
    }
    __syncthreads();
    #pragma unroll
    for (int kc = 0; kc < 2; ++kc) {
      short8 af[4], bfr[4];
      #pragma unroll
      for (int mt = 0; mt < 4; ++mt)
        af[mt] = *(const short8*)&As[wm*64 + mt*16 + Ln][kc*32 + Lq*8];
      #pragma unroll
      for (int nt = 0; nt < 4; ++nt)
        bfr[nt] = *(const short8*)&Bs[wn*64 + nt*16 + Ln][kc*32 + Lq*8];
      #pragma unroll
      for (int mt = 0; mt < 4; ++mt)
        #pragma unroll
        for (int nt = 0; nt < 4; ++nt)
          acc[mt][nt] = __builtin_amdgcn_mfma_f32_16x16x32_bf16(af[mt], bfr[nt], acc[mt][nt], 0, 0, 0);
    }
    __syncthreads();
  }
  #pragma unroll
  for (int mt = 0; mt < 4; ++mt)
    #pragma unroll
    for (int nt = 0; nt < 4; ++nt)
      #pragma unroll
      for (int r = 0; r < 4; ++r) {
        size_t row = m0 + wm*64 + mt*16 + Lq*4 + r;
        int col = n0 + wn*64 + nt*16 + Ln;
        if (OBF) ((unsigned short*)C)[row * N + col] = f2bf(acc[mt][nt][r]);
        else     ((float*)C)[row * N + col] = acc[mt][nt][r];
      }
}

// ---------------- fp16x3 split GEMM (fp32-accurate q) -----------------------
// C[M,N] fp32 = Ah*Bh^T + Ah*Bl^T + Al*Bh^T, fp16 operands, Bt layout [N][K].
// 128x128 tile, BK=32, 4 waves (2x2).
template<int N, int KD>
__global__ __launch_bounds__(256)
void gemm_f16x3(const unsigned short* __restrict__ Ah,
                const unsigned short* __restrict__ Al,
                const unsigned short* __restrict__ Bh,
                const unsigned short* __restrict__ Bl,
                float* __restrict__ C) {
  __shared__ __align__(16) unsigned short As[2][128][40];  // [hi/lo][m][k], +8 pad
  __shared__ __align__(16) unsigned short Bs[2][128][40];
  const int tid = threadIdx.x;
  const int w = tid >> 6, L = tid & 63, Ln = L & 15, Lq = L >> 4;
  const int wm = w & 1, wn = w >> 1;
  const int m0 = blockIdx.y * 128, n0 = blockIdx.x * 128;

  floatx4 acc[4][4];
  #pragma unroll
  for (int mt = 0; mt < 4; ++mt)
    #pragma unroll
    for (int nt = 0; nt < 4; ++nt) acc[mt][nt] = (floatx4)0.f;

  for (int kt = 0; kt < KD; kt += 32) {
    #pragma unroll
    for (int i = 0; i < 2; ++i) {
      int u = tid + i * 256;               // 512 uint4 units per operand
      int row = u >> 2, g = u & 3;
      size_t offA = (size_t)(m0 + row) * KD + kt + g * 8;
      size_t offB = (size_t)(n0 + row) * KD + kt + g * 8;
      *(uint4*)&As[0][row][g*8] = *(const uint4*)(Ah + offA);
      *(uint4*)&As[1][row][g*8] = *(const uint4*)(Al + offA);
      *(uint4*)&Bs[0][row][g*8] = *(const uint4*)(Bh + offB);
      *(uint4*)&Bs[1][row][g*8] = *(const uint4*)(Bl + offB);
    }
    __syncthreads();
    half8 afh[4], afl[4], bfh[4], bfl[4];
    #pragma unroll
    for (int mt = 0; mt < 4; ++mt) {
      afh[mt] = *(const half8*)&As[0][wm*64 + mt*16 + Ln][Lq*8];
      afl[mt] = *(const half8*)&As[1][wm*64 + mt*16 + Ln][Lq*8];
    }
    #pragma unroll
    for (int nt = 0; nt < 4; ++nt) {
      bfh[nt] = *(const half8*)&Bs[0][wn*64 + nt*16 + Ln][Lq*8];
      bfl[nt] = *(const half8*)&Bs[1][wn*64 + nt*16 + Ln][Lq*8];
    }
    #pragma unroll
    for (int mt = 0; mt < 4; ++mt)
      #pragma unroll
      for (int nt = 0; nt < 4; ++nt) {
        acc[mt][nt] = __builtin_amdgcn_mfma_f32_16x16x32_f16(afh[mt], bfh[nt], acc[mt][nt], 0, 0, 0);
        acc[mt][nt] = __builtin_amdgcn_mfma_f32_16x16x32_f16(afh[mt], bfl[nt], acc[mt][nt], 0, 0, 0);
        acc[mt][nt] = __builtin_amdgcn_mfma_f32_16x16x32_f16(afl[mt], bfh[nt], acc[mt][nt], 0, 0, 0);
      }
    __syncthreads();
  }
  #pragma unroll
  for (int mt = 0; mt < 4; ++mt)
    #pragma unroll
    for (int nt = 0; nt < 4; ++nt)
      #pragma unroll
      for (int r = 0; r < 4; ++r) {
        size_t row = m0 + wm*64 + mt*16 + Lq*4 + r;
        int col = n0 + wn*64 + nt*16 + Ln;
        C[row * N + col] = acc[mt][nt][r];
      }
}

// ---------------- causal flash attention, bf16 MFMA, paired q-tiles ---------
// Block ib pairs q-tiles (15-ib, ib): exactly 34 tile-steps per block (balanced),
// lo tile reuses the K/V staged for the hi tile. K/V double-buffered: one
// barrier per step, global loads overlapped with compute.
__global__ __launch_bounds__(256, 2)
void flash_mfma(const float* __restrict__ qf, const unsigned short* __restrict__ kv,
                unsigned short* __restrict__ y) {
  __shared__ __align__(16) unsigned short Ks[2][64 * 64];   // [buf][key][d] swizzled
  __shared__ __align__(16) unsigned short Vt[2][64 * 64];   // [buf][d][key] swizzled
  __shared__ __align__(16) unsigned short Ps[4][32 * 64];   // per-wave [qrow][key]
  const int ib = blockIdx.x;                 // 0..7
  const int bh = blockIdx.y;
  const int b = bh >> 4, h = bh & 15;
  const int tid = threadIdx.x;
  const int w = tid >> 6, L = tid & 63;
  const int Ln = L & 15, Lq = L >> 4;
  const size_t base = (size_t)b * Tseq;
  const int hof = h * 64;
  const int qtl[2] = {15 - ib, ib};
  const int nkt = 2 * qtl[0] + 2;            // iterations (hi tile length)
  const int nlo = 2 * qtl[1] + 2;            // lo tile active while kt < nlo

  // Q A-fragments for both tiles, fp32 global -> bf16 regs
  short8 qfr[2][2][2];
  #pragma unroll
  for (int t = 0; t < 2; ++t) {
    const int q0t = qtl[t] * 128;
    #pragma unroll
    for (int mt = 0; mt < 2; ++mt) {
      const float* qp = qf + (base + q0t + w*32 + mt*16 + Ln) * Ed + hof;
      #pragma unroll
      for (int kc = 0; kc < 2; ++kc) {
        float v[8];
        *(float4*)&v[0] = *(const float4*)(qp + kc*32 + Lq*8);
        *(float4*)&v[4] = *(const float4*)(qp + kc*32 + Lq*8 + 4);
        short8 tt;
        #pragma unroll
        for (int j = 0; j < 8; ++j) tt[j] = (short)f2bf(v[j]);
        qfr[t][mt][kc] = tt;
      }
    }
  }

  float m_i[2][2][4], l_i[2][2][4];
  floatx4 O[2][2][4];
  #pragma unroll
  for (int t = 0; t < 2; ++t)
    #pragma unroll
    for (int mt = 0; mt < 2; ++mt) {
      #pragma unroll
      for (int r = 0; r < 4; ++r) { m_i[t][mt][r] = -3.0e38f; l_i[t][mt][r] = 0.f; }
      #pragma unroll
      for (int nt = 0; nt < 4; ++nt) O[t][mt][nt] = (floatx4)0.f;
    }

  // prologue: stage tile 0 into buffer 0
  #pragma unroll
  for (int i = 0; i < 2; ++i) {
    int u = tid + i * 256;                   // 512 uint4 units per operand
    int c = u >> 3, g = u & 7;
    const unsigned short* kvp = kv + (base + c) * 2048 + hof + g * 8;
    uint4 k4 = *(const uint4*)kvp;
    *(uint4*)&Ks[0][c*64 + ((g ^ (c & 7)) << 3)] = k4;
    unsigned short vv[8];
    *(uint4*)vv = *(const uint4*)(kvp + 1024);
    #pragma unroll
    for (int j = 0; j < 8; ++j) Vt[0][swz(g*8 + j, c)] = vv[j];
  }
  __syncthreads();

  int cur = 0;
  for (int kt = 0; kt < nkt; ++kt) {
    // ---- issue global loads for next tile (overlap with compute) ----
    uint4 kreg[2], vreg[2];
    const bool pre = (kt + 1 < nkt);
    if (pre) {
      #pragma unroll
      for (int i = 0; i < 2; ++i) {
        int u = tid + i * 256;
        int c = u >> 3, g = u & 7;
        const unsigned short* kvp = kv + (base + (kt+1)*64 + c) * 2048 + hof + g * 8;
        kreg[i] = *(const uint4*)kvp;
        vreg[i] = *(const uint4*)(kvp + 1024);
      }
    }

    // ---- compute both tiles on buffer `cur` ----
    #pragma unroll
    for (int t = 0; t < 2; ++t) {
      if (t == 0 || kt < nlo) {
        // S = Q K^T
        short8 kb[4][2];
        #pragma unroll
        for (int nt = 0; nt < 4; ++nt) {
          int krow = nt*16 + Ln;
          #pragma unroll
          for (int kc = 0; kc < 2; ++kc)
            kb[nt][kc] = *(const short8*)&Ks[cur][krow*64 + ((((kc*4 + Lq) ^ (krow & 7)) << 3))];
        }
        floatx4 S[2][4];
        #pragma unroll
        for (int mt = 0; mt < 2; ++mt)
          #pragma unroll
          for (int nt = 0; nt < 4; ++nt) {
            floatx4 a = (floatx4)0.f;
            a = __builtin_amdgcn_mfma_f32_16x16x32_bf16(qfr[t][mt][0], kb[nt][0], a, 0, 0, 0);
            a = __builtin_amdgcn_mfma_f32_16x16x32_bf16(qfr[t][mt][1], kb[nt][1], a, 0, 0, 0);
            S[mt][nt] = a;
          }
        #pragma unroll
        for (int mt = 0; mt < 2; ++mt)
          #pragma unroll
          for (int nt = 0; nt < 4; ++nt)
            #pragma unroll
            for (int r = 0; r < 4; ++r) S[mt][nt][r] *= 0.125f;
        if (kt >= 2*qtl[t]) {
          const int q0t = qtl[t] * 128;
          #pragma unroll
          for (int mt = 0; mt < 2; ++mt) {
            int rowg = q0t + w*32 + mt*16 + Lq*4;
            #pragma unroll
            for (int nt = 0; nt < 4; ++nt) {
              int colg = kt*64 + nt*16 + Ln;
              #pragma unroll
              for (int r = 0; r < 4; ++r)
                if (colg > rowg + r) S[mt][nt][r] = -3.0e38f;
            }
          }
        }

        // online softmax
        #pragma unroll
        for (int mt = 0; mt < 2; ++mt) {
          #pragma unroll
          for (int r = 0; r < 4; ++r) {
            float mx = fmaxf(fmaxf(S[mt][0][r], S[mt][1][r]),
                             fmaxf(S[mt][2][r], S[mt][3][r]));
            mx = fmaxf(mx, __shfl_xor(mx, 1));
            mx = fmaxf(mx, __shfl_xor(mx, 2));
            mx = fmaxf(mx, __shfl_xor(mx, 4));
            mx = fmaxf(mx, __shfl_xor(mx, 8));
            float mnew = fmaxf(m_i[t][mt][r], mx);
            float alpha = __expf(m_i[t][mt][r] - mnew);
            m_i[t][mt][r] = mnew;
            float rs = 0.f;
            #pragma unroll
            for (int nt = 0; nt < 4; ++nt) {
              float p = __expf(S[mt][nt][r] - mnew);
              S[mt][nt][r] = p;
              rs += p;
            }
            rs += __shfl_xor(rs, 1);
            rs += __shfl_xor(rs, 2);
            rs += __shfl_xor(rs, 4);
            rs += __shfl_xor(rs, 8);
            l_i[t][mt][r] = l_i[t][mt][r] * alpha + rs;
            #pragma unroll
            for (int nt = 0; nt < 4; ++nt) O[t][mt][nt][r] *= alpha;
            int prow = mt*16 + Lq*4 + r;
            #pragma unroll
            for (int nt = 0; nt < 4; ++nt)
              Ps[w][swz(prow, nt*16 + Ln)] = f2bf(S[mt][nt][r]);
          }
        }

        // O += P V
        short8 vb[4][2], pf[2][2];
        #pragma unroll
        for (int nt = 0; nt < 4; ++nt) {
          int vrow = nt*16 + Ln;
          #pragma unroll
          for (int kc = 0; kc < 2; ++kc)
            vb[nt][kc] = *(const short8*)&Vt[cur][vrow*64 + ((((kc*4 + Lq) ^ (vrow & 7)) << 3))];
        }
        #pragma unroll
        for (int mt = 0; mt < 2; ++mt) {
          int prow = mt*16 + Ln;
          #pragma unroll
          for (int kc = 0; kc < 2; ++kc)
            pf[mt][kc] = *(const short8*)&Ps[w][prow*64 + ((((kc*4 + Lq) ^ (prow & 7)) << 3))];
        }
        #pragma unroll
        for (int mt = 0; mt < 2; ++mt)
          #pragma unroll
          for (int nt = 0; nt < 4; ++nt) {
            O[t][mt][nt] = __builtin_amdgcn_mfma_f32_16x16x32_bf16(pf[mt][0], vb[nt][0], O[t][mt][nt], 0, 0, 0);
            O[t][mt][nt] = __builtin_amdgcn_mfma_f32_16x16x32_bf16(pf[mt][1], vb[nt][1], O[t][mt][nt], 0, 0, 0);
          }
      }
    }

    // ---- write prefetched tile into the other buffer ----
    if (pre) {
      #pragma unroll
      for (int i = 0; i < 2; ++i) {
        int u = tid + i * 256;
        int c = u >> 3, g = u & 7;
        *(uint4*)&Ks[cur^1][c*64 + ((g ^ (c & 7)) << 3)] = kreg[i];
        unsigned short vv[8];
        *(uint4*)vv = vreg[i];
        #pragma unroll
        for (int j = 0; j < 8; ++j) Vt[cur^1][swz(g*8 + j, c)] = vv[j];
      }
    }
    __syncthreads();
    cur ^= 1;
  }

  // epilogue -> y bf16, both tiles
  #pragma unroll
  for (int t = 0; t < 2; ++t) {
    const int q0t = qtl[t] * 128;
    #pragma unroll
    for (int mt = 0; mt < 2; ++mt) {
      #pragma unroll
      for (int r = 0; r < 4; ++r) {
        float inv = 1.f / l_i[t][mt][r];
        size_t rb = (base + q0t + w*32 + mt*16 + Lq*4 + r) * Ed + hof;
        #pragma unroll
        for (int nt = 0; nt < 4; ++nt)
          y[rb + nt*16 + Ln] = f2bf(O[t][mt][nt][r] * inv);
      }
    }
  }
}

// ---------------- mem attention (K=3, scale 4096) + gated fusion ------------
__global__ __launch_bounds__(256)
void mem_gate(const float* __restrict__ qf, const float* __restrict__ mem_k,
              const float* __restrict__ mem_v, const float* __restrict__ gate,
              unsigned short* __restrict__ y) {
  const int tid = threadIdx.x;
  const int lane = tid & 63;
  const int g = (blockIdx.x << 2) | (tid >> 6);
  const int h = g & 15;
  const int bt = g >> 4;
  const float q = qf[(size_t)bt * Ed + h*64 + lane];
  const size_t mb = ((size_t)bt * 3) * Ed + h*64 + lane;

  float s[3];
  #pragma unroll
  for (int k = 0; k < 3; ++k) {
    float p = q * mem_k[mb + (size_t)k * Ed];
    p += __shfl_xor(p, 1);  p += __shfl_xor(p, 2);  p += __shfl_xor(p, 4);
    p += __shfl_xor(p, 8);  p += __shfl_xor(p, 16); p += __shfl_xor(p, 32);
    s[k] = p * 4096.0f;
  }
  float mx = fmaxf(s[0], fmaxf(s[1], s[2]));
  float w0 = __expf(s[0] - mx), w1 = __expf(s[1] - mx), w2 = __expf(s[2] - mx);
  float inv = 1.f / (w0 + w1 + w2);
  float ov = (w0 * mem_v[mb] + w1 * mem_v[mb + Ed] + w2 * mem_v[mb + 2*Ed]) * inv;
  float gb = gate[h];
  unsigned short* yp = y + (size_t)bt * Ed + h*64 + lane;
  float yv = bf2f(*yp);
  *yp = f2bf(ov * gb + yv * (1.f - gb));
}

extern "C" void kernel_launch(void* const* d_in, const int* in_sizes, int n_in,
                              void* d_out, int out_size, void* d_ws, size_t ws_size,
                              hipStream_t stream) {
  const float* x      = (const float*)d_in[0];
  const float* mem_k  = (const float*)d_in[1];
  const float* mem_v  = (const float*)d_in[2];
  const float* W_attn = (const float*)d_in[3];
  const float* W_proj = (const float*)d_in[4];
  const float* gate   = (const float*)d_in[5];
  float* out = (float*)d_out;

  // workspace layout (~107 MB), unchanged from previous session
  float* qf32          = (float*)d_ws;                       // [M,1024] f32
  unsigned short* kvb  = (unsigned short*)(qf32 + (size_t)MROWS*Ed);  // [M,2048] bf16
  unsigned short* ybf  = kvb + (size_t)MROWS*2048;           // [M,1024] bf16
  unsigned short* xb   = ybf + (size_t)MROWS*Ed;             // [M,1024] bf16
  unsigned short* wkv  = xb  + (size_t)MROWS*Ed;             // [2048,1024] bf16
  unsigned short* wp   = wkv + (size_t)2048*Ed;              // [1024,1024] bf16
  // scratch aliases (dead before their region's real use):
  //  - xh/xl (fp16 split of x) live only until gemm_f16x3; park them in d_out
  //    (out is written only by the final projection GEMM).
  //  - wqh/wql (fp16 split of W_attn[:, :1024]^T) live only until gemm_f16x3;
  //    park them in kvb (kv GEMM writes kvb after q is done).
  unsigned short* xh  = (unsigned short*)d_out;              // [M,1024] f16
  unsigned short* xl  = xh + (size_t)MROWS*Ed;               // [M,1024] f16
  unsigned short* wqh = kvb;                                 // [1024,1024] f16
  unsigned short* wql = wqh + (size_t)Ed*Ed;                 // [1024,1024] f16

  // 0) casts / transposes / splits
  cast_split_k<<<(MROWS*Ed/4 + 255)/256, 256, 0, stream>>>(x, xb, xh, xl, MROWS*Ed/4);
  transpose_split<<<dim3(Ed/64, Ed/64), 256, 0, stream>>>(W_attn, E3, 0, wqh, wql, Ed);
  transpose_cast<<<dim3(2048/64, Ed/64), 256, 0, stream>>>(W_attn, E3, Ed, wkv, Ed);
  transpose_cast<<<dim3(Ed/64, Ed/64), 256, 0, stream>>>(W_proj, Ed, 0, wp, Ed);
  // 1) q = x @ W_attn[:, :1024] via fp16 hi/lo 3-product MFMA (fp32-accurate)
  gemm_f16x3<Ed, Ed>
      <<<dim3(Ed/128, MROWS/128), 256, 0, stream>>>(xh, xl, wqh, wql, qf32);
  // 2) kv = xb @ wkv^T  (bf16 MFMA, bf16 out; overwrites wqh/wql scratch)
  gemm_bf16<2048, Ed, true>
      <<<dim3(2048/128, MROWS/128), 256, 0, stream>>>(xb, wkv, kvb);
  // 3) y = causal SDPA (paired q-tiles, double-buffered K/V)
  flash_mfma<<<dim3(8, Bsz*Hh), 256, 0, stream>>>(qf32, kvb, ybf);
  // 4) y = gate*memattn + (1-gate)*y  (in place, bf16)
  mem_gate<<<(MROWS*Hh)/4, 256, 0, stream>>>(qf32, mem_k, mem_v, gate, ybf);
  // 5) out = y @ wp^T  (bf16 MFMA, fp32 out; xh/xl scratch dead by now)
  gemm_bf16<Ed, Ed, false>
      <<<dim3(Ed/128, MROWS/128), 256, 0, stream>>>(ybf, wp, out);
}

// Round 2
// 608.474 us; speedup vs baseline: 1.2977x; 1.2391x over previous
//
#include <hip/hip_runtime.h>
#include <math.h>

#define Bsz 4
#define Tseq 2048
#define Ed 1024
#define Hh 16
#define E3 (3*Ed)
#define MROWS (Bsz*Tseq)

typedef short short8 __attribute__((ext_vector_type(8)));
typedef _Float16 half8 __attribute__((ext_vector_type(8)));
typedef float floatx4 __attribute__((ext_vector_type(4)));

__device__ __forceinline__ unsigned short f2bf(float f) {
  unsigned int u = __builtin_bit_cast(unsigned int, f);
  u += 0x7fffu + ((u >> 16) & 1u);           // RNE (finite inputs)
  return (unsigned short)(u >> 16);
}
__device__ __forceinline__ float bf2f(unsigned short u) {
  return __builtin_bit_cast(float, ((unsigned int)u) << 16);
}
__device__ __forceinline__ unsigned short f2h(float f) {
  _Float16 h = (_Float16)f;
  return __builtin_bit_cast(unsigned short, h);
}
__device__ __forceinline__ float h2f(unsigned short u) {
  return (float)__builtin_bit_cast(_Float16, u);
}
// swizzled element index in a 64-col bf16 tile (group-of-8 XOR on row)
__device__ __forceinline__ int swz(int row, int col) {
  return row * 64 + ((((col >> 3) ^ (row & 7)) << 3) | (col & 7));
}

// ---------------- x -> bf16 + fp16 hi/lo split -------------------------------
__global__ __launch_bounds__(256)
void cast_split_k(const float* __restrict__ s, unsigned short* __restrict__ bb,
                  unsigned short* __restrict__ hh, unsigned short* __restrict__ ll,
                  int n4) {
  int i = blockIdx.x * 256 + threadIdx.x;
  if (i >= n4) return;
  float4 v = ((const float4*)s)[i];
  float vv[4] = {v.x, v.y, v.z, v.w};
  unsigned short ob[4], oh[4], ol[4];
  #pragma unroll
  for (int j = 0; j < 4; ++j) {
    ob[j] = f2bf(vv[j]);
    unsigned short h = f2h(vv[j]);
    oh[j] = h;
    ol[j] = f2h(vv[j] - h2f(h));
  }
  ((uint2*)bb)[i] = *(uint2*)ob;
  ((uint2*)hh)[i] = *(uint2*)oh;
  ((uint2*)ll)[i] = *(uint2*)ol;
}

// ---------------- fp32 [K][ld] (col window c0) -> bf16 [N][K] transpose -----
__global__ __launch_bounds__(256)
void transpose_cast(const float* __restrict__ src, int ld, int c0,
                    unsigned short* __restrict__ dst, int Krows) {
  __shared__ float t[64][65];
  const int kb = blockIdx.y * 64, nb = blockIdx.x * 64;
  const int tid = threadIdx.x;
  #pragma unroll
  for (int i = 0; i < 4; ++i) {
    int u = tid + i * 256;                 // 1024 float4 units
    int r = u >> 4, c4 = u & 15;
    float4 v = *(const float4*)(src + (size_t)(kb + r) * ld + c0 + nb + c4 * 4);
    t[r][c4*4+0] = v.x; t[r][c4*4+1] = v.y; t[r][c4*4+2] = v.z; t[r][c4*4+3] = v.w;
  }
  __syncthreads();
  #pragma unroll
  for (int i = 0; i < 2; ++i) {
    int u = tid + i * 256;                 // 512 units: 64 n-rows x 8 k-groups
    int rn = u >> 3, g = u & 7;
    unsigned short o[8];
    #pragma unroll
    for (int j = 0; j < 8; ++j) o[j] = f2bf(t[g*8+j][rn]);
    *(uint4*)(dst + (size_t)(nb + rn) * Krows + kb + g * 8) = *(uint4*)o;
  }
}

// ---------------- fp32 [K][ld] (col window c0) -> fp16 hi/lo [N][K] ---------
__global__ __launch_bounds__(256)
void transpose_split(const float* __restrict__ src, int ld, int c0,
                     unsigned short* __restrict__ dh, unsigned short* __restrict__ dl,
                     int Krows) {
  __shared__ float t[64][65];
  const int kb = blockIdx.y * 64, nb = blockIdx.x * 64;
  const int tid = threadIdx.x;
  #pragma unroll
  for (int i = 0; i < 4; ++i) {
    int u = tid + i * 256;
    int r = u >> 4, c4 = u & 15;
    float4 v = *(const float4*)(src + (size_t)(kb + r) * ld + c0 + nb + c4 * 4);
    t[r][c4*4+0] = v.x; t[r][c4*4+1] = v.y; t[r][c4*4+2] = v.z; t[r][c4*4+3] = v.w;
  }
  __syncthreads();
  #pragma unroll
  for (int i = 0; i < 2; ++i) {
    int u = tid + i * 256;
    int rn = u >> 3, g = u & 7;
    unsigned short oh[8], ol[8];
    #pragma unroll
    for (int j = 0; j < 8; ++j) {
      float f = t[g*8+j][rn];
      unsigned short h = f2h(f);
      oh[j] = h;
      ol[j] = f2h(f - h2f(h));
    }
    size_t off = (size_t)(nb + rn) * Krows + kb + g * 8;
    *(uint4*)(dh + off) = *(uint4*)oh;
    *(uint4*)(dl + off) = *(uint4*)ol;
  }
}

// ---------------- bf16 MFMA GEMM: C[M,N] = A[M,K] * Bt[N,K]^T ---------------
// 128x128 tile, BK=64, 4 waves (2x2), each wave 64x64 via 4x4 16x16x32 MFMAs.
template<int N, int KD, bool OBF>
__global__ __launch_bounds__(256)
void gemm_bf16(const unsigned short* __restrict__ A,
               const unsigned short* __restrict__ Bt,
               void* __restrict__ C) {
  __shared__ __align__(16) unsigned short As[128][72];  // [m][k], +8 pad
  __shared__ __align__(16) unsigned short Bs[128][72];  // [n][k], +8 pad
  const int tid = threadIdx.x;
  const int w = tid >> 6, L = tid & 63, Ln = L & 15, Lq = L >> 4;
  const int wm = w & 1, wn = w >> 1;
  const int m0 = blockIdx.y * 128, n0 = blockIdx.x * 128;

  floatx4 acc[4][4];
  #pragma unroll
  for (int mt = 0; mt < 4; ++mt)
    #pragma unroll
    for (int nt = 0; nt < 4; ++nt) acc[mt][nt] = (floatx4)0.f;

  for (int kt = 0; kt < KD; kt += 64) {
    #pragma unroll
    for (int i = 0; i < 4; ++i) {
      int u = tid + i * 256;               // 1024 uint4 units per operand
      int row = u >> 3, g = u & 7;
      *(uint4*)&As[row][g*8] = *(const uint4*)(A + (size_t)(m0 + row) * KD + kt + g * 8);
      *(uint4*)&Bs[row][g*8] = *(const uint4*)(Bt + (size_t)(n0 + row) * KD + kt + g * 8);
    }
    __syncthreads();
    #pragma unroll
    for (int kc = 0; kc < 2; ++kc) {
      short8 af[4], bfr[4];
      #pragma unroll
      for (int mt = 0; mt < 4; ++mt)
        af[mt] = *(const short8*)&As[wm*64 + mt*16 + Ln][kc*32 + Lq*8];
      #pragma unroll
      for (int nt = 0; nt < 4; ++nt)
        bfr[nt] = *(const short8*)&Bs[wn*64 + nt*16 + Ln][kc*32 + Lq*8];
      #pragma unroll
      for (int mt = 0; mt < 4; ++mt)
        #pragma unroll
        for (int nt = 0; nt < 4; ++nt)
          acc[mt][nt] = __builtin_amdgcn_mfma_f32_16x16x32_bf16(af[mt], bfr[nt], acc[mt][nt], 0, 0, 0);
    }
    __syncthreads();
  }
  #pragma unroll
  for (int mt = 0; mt < 4; ++mt)
    #pragma unroll
    for (int nt = 0; nt < 4; ++nt)
      #pragma unroll
      for (int r = 0; r < 4; ++r) {
        size_t row = m0 + wm*64 + mt*16 + Lq*4 + r;
        int col = n0 + wn*64 + nt*16 + Ln;
        if (OBF) ((unsigned short*)C)[row * N + col] = f2bf(acc[mt][nt][r]);
        else     ((float*)C)[row * N + col] = acc[mt][nt][r];
      }
}

// ---------------- fp16x3 split GEMM (fp32-accurate q) -----------------------
// C[M,N] fp32 = Ah*Bh^T + Ah*Bl^T + Al*Bh^T, fp16 operands, Bt layout [N][K].
// 128x128 tile, BK=32, 4 waves (2x2).
template<int N, int KD>
__global__ __launch_bounds__(256)
void gemm_f16x3(const unsigned short* __restrict__ Ah,
                const unsigned short* __restrict__ Al,
                const unsigned short* __restrict__ Bh,
                const unsigned short* __restrict__ Bl,
                float* __restrict__ C) {
  __shared__ __align__(16) unsigned short As[2][128][40];  // [hi/lo][m][k], +8 pad
  __shared__ __align__(16) unsigned short Bs[2][128][40];
  const int tid = threadIdx.x;
  const int w = tid >> 6, L = tid & 63, Ln = L & 15, Lq = L >> 4;
  const int wm = w & 1, wn = w >> 1;
  const int m0 = blockIdx.y * 128, n0 = blockIdx.x * 128;

  floatx4 acc[4][4];
  #pragma unroll
  for (int mt = 0; mt < 4; ++mt)
    #pragma unroll
    for (int nt = 0; nt < 4; ++nt) acc[mt][nt] = (floatx4)0.f;

  for (int kt = 0; kt < KD; kt += 32) {
    #pragma unroll
    for (int i = 0; i < 2; ++i) {
      int u = tid + i * 256;               // 512 uint4 units per operand
      int row = u >> 2, g = u & 3;
      size_t offA = (size_t)(m0 + row) * KD + kt + g * 8;
      size_t offB = (size_t)(n0 + row) * KD + kt + g * 8;
      *(uint4*)&As[0][row][g*8] = *(const uint4*)(Ah + offA);
      *(uint4*)&As[1][row][g*8] = *(const uint4*)(Al + offA);
      *(uint4*)&Bs[0][row][g*8] = *(const uint4*)(Bh + offB);
      *(uint4*)&Bs[1][row][g*8] = *(const uint4*)(Bl + offB);
    }
    __syncthreads();
    half8 afh[4], afl[4], bfh[4], bfl[4];
    #pragma unroll
    for (int mt = 0; mt < 4; ++mt) {
      afh[mt] = *(const half8*)&As[0][wm*64 + mt*16 + Ln][Lq*8];
      afl[mt] = *(const half8*)&As[1][wm*64 + mt*16 + Ln][Lq*8];
    }
    #pragma unroll
    for (int nt = 0; nt < 4; ++nt) {
      bfh[nt] = *(const half8*)&Bs[0][wn*64 + nt*16 + Ln][Lq*8];
      bfl[nt] = *(const half8*)&Bs[1][wn*64 + nt*16 + Ln][Lq*8];
    }
    #pragma unroll
    for (int mt = 0; mt < 4; ++mt)
      #pragma unroll
      for (int nt = 0; nt < 4; ++nt) {
        acc[mt][nt] = __builtin_amdgcn_mfma_f32_16x16x32_f16(afh[mt], bfh[nt], acc[mt][nt], 0, 0, 0);
        acc[mt][nt] = __builtin_amdgcn_mfma_f32_16x16x32_f16(afh[mt], bfl[nt], acc[mt][nt], 0, 0, 0);
        acc[mt][nt] = __builtin_amdgcn_mfma_f32_16x16x32_f16(afl[mt], bfh[nt], acc[mt][nt], 0, 0, 0);
      }
    __syncthreads();
  }
  #pragma unroll
  for (int mt = 0; mt < 4; ++mt)
    #pragma unroll
    for (int nt = 0; nt < 4; ++nt)
      #pragma unroll
      for (int r = 0; r < 4; ++r) {
        size_t row = m0 + wm*64 + mt*16 + Lq*4 + r;
        int col = n0 + wn*64 + nt*16 + Ln;
        C[row * N + col] = acc[mt][nt][r];
      }
}

// ---------------- causal flash attention, bf16 MFMA, sequential paired tiles
// Block ib runs q-tile (15-ib) to completion, then q-tile ib: 34 tile-steps
// per block (balanced makespan), but only ONE tile's register state live at a
// time (no spills). K/V double-buffered through registers: one barrier/step.
__global__ __launch_bounds__(256)
void flash_mfma(const float* __restrict__ qf, const unsigned short* __restrict__ kv,
                unsigned short* __restrict__ y) {
  __shared__ __align__(16) unsigned short Ks[2][64 * 64];   // [buf][key][d] swizzled
  __shared__ __align__(16) unsigned short Vt[2][64 * 64];   // [buf][d][key] swizzled
  __shared__ __align__(16) unsigned short Ps[4][32 * 64];   // per-wave [qrow][key]
  const int ib = blockIdx.x;                 // 0..7
  const int bh = blockIdx.y;
  const int b = bh >> 4, h = bh & 15;
  const int tid = threadIdx.x;
  const int w = tid >> 6, L = tid & 63;
  const int Ln = L & 15, Lq = L >> 4;
  const size_t base = (size_t)b * Tseq;
  const int hof = h * 64;

  for (int t = 0; t < 2; ++t) {
    const int qt = t ? ib : 15 - ib;
    const int q0 = qt * 128;
    const int nkt = 2 * qt + 2;

    // Q A-fragments, fp32 global -> bf16 regs
    short8 qfr[2][2];
    #pragma unroll
    for (int mt = 0; mt < 2; ++mt) {
      const float* qp = qf + (base + q0 + w*32 + mt*16 + Ln) * Ed + hof;
      #pragma unroll
      for (int kc = 0; kc < 2; ++kc) {
        float v[8];
        *(float4*)&v[0] = *(const float4*)(qp + kc*32 + Lq*8);
        *(float4*)&v[4] = *(const float4*)(qp + kc*32 + Lq*8 + 4);
        short8 tt;
        #pragma unroll
        for (int j = 0; j < 8; ++j) tt[j] = (short)f2bf(v[j]);
        qfr[mt][kc] = tt;
      }
    }

    float m_i[2][4], l_i[2][4];
    floatx4 O[2][4];
    #pragma unroll
    for (int mt = 0; mt < 2; ++mt) {
      #pragma unroll
      for (int r = 0; r < 4; ++r) { m_i[mt][r] = -3.0e38f; l_i[mt][r] = 0.f; }
      #pragma unroll
      for (int nt = 0; nt < 4; ++nt) O[mt][nt] = (floatx4)0.f;
    }

    // prologue: stage kt=0 into buffer 0
    #pragma unroll
    for (int i = 0; i < 2; ++i) {
      int u = tid + i * 256;                 // 512 uint4 units per operand
      int c = u >> 3, g = u & 7;
      const unsigned short* kvp = kv + (base + c) * 2048 + hof + g * 8;
      uint4 k4 = *(const uint4*)kvp;
      *(uint4*)&Ks[0][c*64 + ((g ^ (c & 7)) << 3)] = k4;
      unsigned short vv[8];
      *(uint4*)vv = *(const uint4*)(kvp + 1024);
      #pragma unroll
      for (int j = 0; j < 8; ++j) Vt[0][swz(g*8 + j, c)] = vv[j];
    }
    __syncthreads();

    int cur = 0;
    for (int kt = 0; kt < nkt; ++kt) {
      // ---- issue global loads for next tile (overlap with compute) ----
      uint4 kreg[2], vreg[2];
      const bool pre = (kt + 1 < nkt);
      if (pre) {
        #pragma unroll
        for (int i = 0; i < 2; ++i) {
          int u = tid + i * 256;
          int c = u >> 3, g = u & 7;
          const unsigned short* kvp = kv + (base + (kt+1)*64 + c) * 2048 + hof + g * 8;
          kreg[i] = *(const uint4*)kvp;
          vreg[i] = *(const uint4*)(kvp + 1024);
        }
      }

      // ---- S = Q K^T ----
      short8 kb[4][2];
      #pragma unroll
      for (int nt = 0; nt < 4; ++nt) {
        int krow = nt*16 + Ln;
        #pragma unroll
        for (int kc = 0; kc < 2; ++kc)
          kb[nt][kc] = *(const short8*)&Ks[cur][krow*64 + ((((kc*4 + Lq) ^ (krow & 7)) << 3))];
      }
      floatx4 S[2][4];
      #pragma unroll
      for (int mt = 0; mt < 2; ++mt)
        #pragma unroll
        for (int nt = 0; nt < 4; ++nt) {
          floatx4 a = (floatx4)0.f;
          a = __builtin_amdgcn_mfma_f32_16x16x32_bf16(qfr[mt][0], kb[nt][0], a, 0, 0, 0);
          a = __builtin_amdgcn_mfma_f32_16x16x32_bf16(qfr[mt][1], kb[nt][1], a, 0, 0, 0);
          S[mt][nt] = a;
        }
      #pragma unroll
      for (int mt = 0; mt < 2; ++mt)
        #pragma unroll
        for (int nt = 0; nt < 4; ++nt)
          #pragma unroll
          for (int r = 0; r < 4; ++r) S[mt][nt][r] *= 0.125f;
      if (kt >= 2*qt) {
        #pragma unroll
        for (int mt = 0; mt < 2; ++mt) {
          int rowg = q0 + w*32 + mt*16 + Lq*4;
          #pragma unroll
          for (int nt = 0; nt < 4; ++nt) {
            int colg = kt*64 + nt*16 + Ln;
            #pragma unroll
            for (int r = 0; r < 4; ++r)
              if (colg > rowg + r) S[mt][nt][r] = -3.0e38f;
          }
        }
      }

      // ---- online softmax ----
      #pragma unroll
      for (int mt = 0; mt < 2; ++mt) {
        #pragma unroll
        for (int r = 0; r < 4; ++r) {
          float mx = fmaxf(fmaxf(S[mt][0][r], S[mt][1][r]),
                           fmaxf(S[mt][2][r], S[mt][3][r]));
          mx = fmaxf(mx, __shfl_xor(mx, 1));
          mx = fmaxf(mx, __shfl_xor(mx, 2));
          mx = fmaxf(mx, __shfl_xor(mx, 4));
          mx = fmaxf(mx, __shfl_xor(mx, 8));
          float mnew = fmaxf(m_i[mt][r], mx);
          float alpha = __expf(m_i[mt][r] - mnew);
          m_i[mt][r] = mnew;
          float rs = 0.f;
          #pragma unroll
          for (int nt = 0; nt < 4; ++nt) {
            float p = __expf(S[mt][nt][r] - mnew);
            S[mt][nt][r] = p;
            rs += p;
          }
          rs += __shfl_xor(rs, 1);
          rs += __shfl_xor(rs, 2);
          rs += __shfl_xor(rs, 4);
          rs += __shfl_xor(rs, 8);
          l_i[mt][r] = l_i[mt][r] * alpha + rs;
          #pragma unroll
          for (int nt = 0; nt < 4; ++nt) O[mt][nt][r] *= alpha;
          int prow = mt*16 + Lq*4 + r;
          #pragma unroll
          for (int nt = 0; nt < 4; ++nt)
            Ps[w][swz(prow, nt*16 + Ln)] = f2bf(S[mt][nt][r]);
        }
      }

      // ---- O += P V ----
      short8 vb[4][2], pf[2][2];
      #pragma unroll
      for (int nt = 0; nt < 4; ++nt) {
        int vrow = nt*16 + Ln;
        #pragma unroll
        for (int kc = 0; kc < 2; ++kc)
          vb[nt][kc] = *(const short8*)&Vt[cur][vrow*64 + ((((kc*4 + Lq) ^ (vrow & 7)) << 3))];
      }
      #pragma unroll
      for (int mt = 0; mt < 2; ++mt) {
        int prow = mt*16 + Ln;
        #pragma unroll
        for (int kc = 0; kc < 2; ++kc)
          pf[mt][kc] = *(const short8*)&Ps[w][prow*64 + ((((kc*4 + Lq) ^ (prow & 7)) << 3))];
      }
      #pragma unroll
      for (int mt = 0; mt < 2; ++mt)
        #pragma unroll
        for (int nt = 0; nt < 4; ++nt) {
          O[mt][nt] = __builtin_amdgcn_mfma_f32_16x16x32_bf16(pf[mt][0], vb[nt][0], O[mt][nt], 0, 0, 0);
          O[mt][nt] = __builtin_amdgcn_mfma_f32_16x16x32_bf16(pf[mt][1], vb[nt][1], O[mt][nt], 0, 0, 0);
        }

      // ---- write prefetched tile into the other buffer ----
      if (pre) {
        #pragma unroll
        for (int i = 0; i < 2; ++i) {
          int u = tid + i * 256;
          int c = u >> 3, g = u & 7;
          *(uint4*)&Ks[cur^1][c*64 + ((g ^ (c & 7)) << 3)] = kreg[i];
          unsigned short vv[8];
          *(uint4*)vv = vreg[i];
          #pragma unroll
          for (int j = 0; j < 8; ++j) Vt[cur^1][swz(g*8 + j, c)] = vv[j];
        }
      }
      __syncthreads();
      cur ^= 1;
    }

    // epilogue -> y bf16
    #pragma unroll
    for (int mt = 0; mt < 2; ++mt) {
      #pragma unroll
      for (int r = 0; r < 4; ++r) {
        float inv = 1.f / l_i[mt][r];
        size_t rb = (base + q0 + w*32 + mt*16 + Lq*4 + r) * Ed + hof;
        #pragma unroll
        for (int nt = 0; nt < 4; ++nt)
          y[rb + nt*16 + Ln] = f2bf(O[mt][nt][r] * inv);
      }
    }
    // after the final barrier of the k-loop no wave touches LDS until the
    // next tile's prologue writes, so no extra sync is needed here
  }
}

// ---------------- mem attention (K=3, scale 4096) + gated fusion ------------
__global__ __launch_bounds__(256)
void mem_gate(const float* __restrict__ qf, const float* __restrict__ mem_k,
              const float* __restrict__ mem_v, const float* __restrict__ gate,
              unsigned short* __restrict__ y) {
  const int tid = threadIdx.x;
  const int lane = tid & 63;
  const int g = (blockIdx.x << 2) | (tid >> 6);
  const int h = g & 15;
  const int bt = g >> 4;
  const float q = qf[(size_t)bt * Ed + h*64 + lane];
  const size_t mb = ((size_t)bt * 3) * Ed + h*64 + lane;

  float s[3];
  #pragma unroll
  for (int k = 0; k < 3; ++k) {
    float p = q * mem_k[mb + (size_t)k * Ed];
    p += __shfl_xor(p, 1);  p += __shfl_xor(p, 2);  p += __shfl_xor(p, 4);
    p += __shfl_xor(p, 8);  p += __shfl_xor(p, 16); p += __shfl_xor(p, 32);
    s[k] = p * 4096.0f;
  }
  float mx = fmaxf(s[0], fmaxf(s[1], s[2]));
  float w0 = __expf(s[0] - mx), w1 = __expf(s[1] - mx), w2 = __expf(s[2] - mx);
  float inv = 1.f / (w0 + w1 + w2);
  float ov = (w0 * mem_v[mb] + w1 * mem_v[mb + Ed] + w2 * mem_v[mb + 2*Ed]) * inv;
  float gb = gate[h];
  unsigned short* yp = y + (size_t)bt * Ed + h*64 + lane;
  float yv = bf2f(*yp);
  *yp = f2bf(ov * gb + yv * (1.f - gb));
}

extern "C" void kernel_launch(void* const* d_in, const int* in_sizes, int n_in,
                              void* d_out, int out_size, void* d_ws, size_t ws_size,
                              hipStream_t stream) {
  const float* x      = (const float*)d_in[0];
  const float* mem_k  = (const float*)d_in[1];
  const float* mem_v  = (const float*)d_in[2];
  const float* W_attn = (const float*)d_in[3];
  const float* W_proj = (const float*)d_in[4];
  const float* gate   = (const float*)d_in[5];
  float* out = (float*)d_out;

  // workspace layout (~107 MB)
  float* qf32          = (float*)d_ws;                       // [M,1024] f32
  unsigned short* kvb  = (unsigned short*)(qf32 + (size_t)MROWS*Ed);  // [M,2048] bf16
  unsigned short* ybf  = kvb + (size_t)MROWS*2048;           // [M,1024] bf16
  unsigned short* xb   = ybf + (size_t)MROWS*Ed;             // [M,1024] bf16
  unsigned short* wkv  = xb  + (size_t)MROWS*Ed;             // [2048,1024] bf16
  unsigned short* wp   = wkv + (size_t)2048*Ed;              // [1024,1024] bf16
  // scratch aliases (dead before their region's real use):
  //  - xh/xl (fp16 split of x) live only until gemm_f16x3; park them in d_out
  //    (out is written only by the final projection GEMM).
  //  - wqh/wql (fp16 split of W_attn[:, :1024]^T) live only until gemm_f16x3;
  //    park them in kvb (kv GEMM writes kvb after q is done).
  unsigned short* xh  = (unsigned short*)d_out;              // [M,1024] f16
  unsigned short* xl  = xh + (size_t)MROWS*Ed;               // [M,1024] f16
  unsigned short* wqh = kvb;                                 // [1024,1024] f16
  unsigned short* wql = wqh + (size_t)Ed*Ed;                 // [1024,1024] f16

  // 0) casts / transposes / splits
  cast_split_k<<<(MROWS*Ed/4 + 255)/256, 256, 0, stream>>>(x, xb, xh, xl, MROWS*Ed/4);
  transpose_split<<<dim3(Ed/64, Ed/64), 256, 0, stream>>>(W_attn, E3, 0, wqh, wql, Ed);
  transpose_cast<<<dim3(2048/64, Ed/64), 256, 0, stream>>>(W_attn, E3, Ed, wkv, Ed);
  transpose_cast<<<dim3(Ed/64, Ed/64), 256, 0, stream>>>(W_proj, Ed, 0, wp, Ed);
  // 1) q = x @ W_attn[:, :1024] via fp16 hi/lo 3-product MFMA (fp32-accurate)
  gemm_f16x3<Ed, Ed>
      <<<dim3(Ed/128, MROWS/128), 256, 0, stream>>>(xh, xl, wqh, wql, qf32);
  // 2) kv = xb @ wkv^T  (bf16 MFMA, bf16 out; overwrites wqh/wql scratch)
  gemm_bf16<2048, Ed, true>
      <<<dim3(2048/128, MROWS/128), 256, 0, stream>>>(xb, wkv, kvb);
  // 3) y = causal SDPA (sequential paired q-tiles, double-buffered K/V)
  flash_mfma<<<dim3(8, Bsz*Hh), 256, 0, stream>>>(qf32, kvb, ybf);
  // 4) y = gate*memattn + (1-gate)*y  (in place, bf16)
  mem_gate<<<(MROWS*Hh)/4, 256, 0, stream>>>(qf32, mem_k, mem_v, gate, ybf);
  // 5) out = y @ wp^T  (bf16 MFMA, fp32 out; xh/xl scratch dead by now)
  gemm_bf16<Ed, Ed, false>
      <<<dim3(Ed/128, MROWS/128), 256, 0, stream>>>(ybf, wp, out);
}

// Round 3
// 528.356 us; speedup vs baseline: 1.4945x; 1.1516x over previous
//
#include <hip/hip_runtime.h>
#include <math.h>

#define Bsz 4
#define Tseq 2048
#define Ed 1024
#define Hh 16
#define E3 (3*Ed)
#define MROWS (Bsz*Tseq)

typedef short short8 __attribute__((ext_vector_type(8)));
typedef _Float16 half8 __attribute__((ext_vector_type(8)));
typedef float floatx4 __attribute__((ext_vector_type(4)));

__device__ __forceinline__ unsigned short f2bf(float f) {
  unsigned int u = __builtin_bit_cast(unsigned int, f);
  u += 0x7fffu + ((u >> 16) & 1u);           // RNE (finite inputs)
  return (unsigned short)(u >> 16);
}
__device__ __forceinline__ float bf2f(unsigned short u) {
  return __builtin_bit_cast(float, ((unsigned int)u) << 16);
}
__device__ __forceinline__ unsigned short f2h(float f) {
  _Float16 h = (_Float16)f;
  return __builtin_bit_cast(unsigned short, h);
}
__device__ __forceinline__ float h2f(unsigned short u) {
  return (float)__builtin_bit_cast(_Float16, u);
}
// swizzled element index in a 64-col bf16 tile (group-of-8 XOR on row)
__device__ __forceinline__ int swz(int row, int col) {
  return row * 64 + ((((col >> 3) ^ (row & 7)) << 3) | (col & 7));
}

// ---------------- x -> bf16 + fp16 hi/lo split -------------------------------
__global__ __launch_bounds__(256)
void cast_split_k(const float* __restrict__ s, unsigned short* __restrict__ bb,
                  unsigned short* __restrict__ hh, unsigned short* __restrict__ ll,
                  int n4) {
  int i = blockIdx.x * 256 + threadIdx.x;
  if (i >= n4) return;
  float4 v = ((const float4*)s)[i];
  float vv[4] = {v.x, v.y, v.z, v.w};
  unsigned short ob[4], oh[4], ol[4];
  #pragma unroll
  for (int j = 0; j < 4; ++j) {
    ob[j] = f2bf(vv[j]);
    unsigned short h = f2h(vv[j]);
    oh[j] = h;
    ol[j] = f2h(vv[j] - h2f(h));
  }
  ((uint2*)bb)[i] = *(uint2*)ob;
  ((uint2*)hh)[i] = *(uint2*)oh;
  ((uint2*)ll)[i] = *(uint2*)ol;
}

// ---------------- fp32 [K][ld] (col window c0) -> bf16 [N][K] transpose -----
__global__ __launch_bounds__(256)
void transpose_cast(const float* __restrict__ src, int ld, int c0,
                    unsigned short* __restrict__ dst, int Krows) {
  __shared__ float t[64][65];
  const int kb = blockIdx.y * 64, nb = blockIdx.x * 64;
  const int tid = threadIdx.x;
  #pragma unroll
  for (int i = 0; i < 4; ++i) {
    int u = tid + i * 256;                 // 1024 float4 units
    int r = u >> 4, c4 = u & 15;
    float4 v = *(const float4*)(src + (size_t)(kb + r) * ld + c0 + nb + c4 * 4);
    t[r][c4*4+0] = v.x; t[r][c4*4+1] = v.y; t[r][c4*4+2] = v.z; t[r][c4*4+3] = v.w;
  }
  __syncthreads();
  #pragma unroll
  for (int i = 0; i < 2; ++i) {
    int u = tid + i * 256;                 // 512 units: 64 n-rows x 8 k-groups
    int rn = u >> 3, g = u & 7;
    unsigned short o[8];
    #pragma unroll
    for (int j = 0; j < 8; ++j) o[j] = f2bf(t[g*8+j][rn]);
    *(uint4*)(dst + (size_t)(nb + rn) * Krows + kb + g * 8) = *(uint4*)o;
  }
}

// ---------------- fp32 [K][ld] (col window c0) -> fp16 hi/lo [N][K] ---------
__global__ __launch_bounds__(256)
void transpose_split(const float* __restrict__ src, int ld, int c0,
                     unsigned short* __restrict__ dh, unsigned short* __restrict__ dl,
                     int Krows) {
  __shared__ float t[64][65];
  const int kb = blockIdx.y * 64, nb = blockIdx.x * 64;
  const int tid = threadIdx.x;
  #pragma unroll
  for (int i = 0; i < 4; ++i) {
    int u = tid + i * 256;
    int r = u >> 4, c4 = u & 15;
    float4 v = *(const float4*)(src + (size_t)(kb + r) * ld + c0 + nb + c4 * 4);
    t[r][c4*4+0] = v.x; t[r][c4*4+1] = v.y; t[r][c4*4+2] = v.z; t[r][c4*4+3] = v.w;
  }
  __syncthreads();
  #pragma unroll
  for (int i = 0; i < 2; ++i) {
    int u = tid + i * 256;
    int rn = u >> 3, g = u & 7;
    unsigned short oh[8], ol[8];
    #pragma unroll
    for (int j = 0; j < 8; ++j) {
      float f = t[g*8+j][rn];
      unsigned short h = f2h(f);
      oh[j] = h;
      ol[j] = f2h(f - h2f(h));
    }
    size_t off = (size_t)(nb + rn) * Krows + kb + g * 8;
    *(uint4*)(dh + off) = *(uint4*)oh;
    *(uint4*)(dl + off) = *(uint4*)ol;
  }
}

// ---------------- bf16 MFMA GEMM: C[M,N] = A[M,K] * Bt[N,K]^T ---------------
// 128x128 tile, BK=64, 4 waves (2x2), each wave 64x64 via 4x4 16x16x32 MFMAs.
template<int N, int KD, bool OBF>
__global__ __launch_bounds__(256)
void gemm_bf16(const unsigned short* __restrict__ A,
               const unsigned short* __restrict__ Bt,
               void* __restrict__ C) {
  __shared__ __align__(16) unsigned short As[128][72];  // [m][k], +8 pad
  __shared__ __align__(16) unsigned short Bs[128][72];  // [n][k], +8 pad
  const int tid = threadIdx.x;
  const int w = tid >> 6, L = tid & 63, Ln = L & 15, Lq = L >> 4;
  const int wm = w & 1, wn = w >> 1;
  const int m0 = blockIdx.y * 128, n0 = blockIdx.x * 128;

  floatx4 acc[4][4];
  #pragma unroll
  for (int mt = 0; mt < 4; ++mt)
    #pragma unroll
    for (int nt = 0; nt < 4; ++nt) acc[mt][nt] = (floatx4)0.f;

  for (int kt = 0; kt < KD; kt += 64) {
    #pragma unroll
    for (int i = 0; i < 4; ++i) {
      int u = tid + i * 256;               // 1024 uint4 units per operand
      int row = u >> 3, g = u & 7;
      *(uint4*)&As[row][g*8] = *(const uint4*)(A + (size_t)(m0 + row) * KD + kt + g * 8);
      *(uint4*)&Bs[row][g*8] = *(const uint4*)(Bt + (size_t)(n0 + row) * KD + kt + g * 8);
    }
    __syncthreads();
    #pragma unroll
    for (int kc = 0; kc < 2; ++kc) {
      short8 af[4], bfr[4];
      #pragma unroll
      for (int mt = 0; mt < 4; ++mt)
        af[mt] = *(const short8*)&As[wm*64 + mt*16 + Ln][kc*32 + Lq*8];
      #pragma unroll
      for (int nt = 0; nt < 4; ++nt)
        bfr[nt] = *(const short8*)&Bs[wn*64 + nt*16 + Ln][kc*32 + Lq*8];
      #pragma unroll
      for (int mt = 0; mt < 4; ++mt)
        #pragma unroll
        for (int nt = 0; nt < 4; ++nt)
          acc[mt][nt] = __builtin_amdgcn_mfma_f32_16x16x32_bf16(af[mt], bfr[nt], acc[mt][nt], 0, 0, 0);
    }
    __syncthreads();
  }
  #pragma unroll
  for (int mt = 0; mt < 4; ++mt)
    #pragma unroll
    for (int nt = 0; nt < 4; ++nt)
      #pragma unroll
      for (int r = 0; r < 4; ++r) {
        size_t row = m0 + wm*64 + mt*16 + Lq*4 + r;
        int col = n0 + wn*64 + nt*16 + Ln;
        if (OBF) ((unsigned short*)C)[row * N + col] = f2bf(acc[mt][nt][r]);
        else     ((float*)C)[row * N + col] = acc[mt][nt][r];
      }
}

// ---------------- fp16x3 split GEMM (fp32-accurate q) -----------------------
// C[M,N] fp32 = Ah*Bh^T + Ah*Bl^T + Al*Bh^T, fp16 operands, Bt layout [N][K].
// 128x128 tile, BK=32, 4 waves (2x2).
template<int N, int KD>
__global__ __launch_bounds__(256)
void gemm_f16x3(const unsigned short* __restrict__ Ah,
                const unsigned short* __restrict__ Al,
                const unsigned short* __restrict__ Bh,
                const unsigned short* __restrict__ Bl,
                float* __restrict__ C) {
  __shared__ __align__(16) unsigned short As[2][128][40];  // [hi/lo][m][k], +8 pad
  __shared__ __align__(16) unsigned short Bs[2][128][40];
  const int tid = threadIdx.x;
  const int w = tid >> 6, L = tid & 63, Ln = L & 15, Lq = L >> 4;
  const int wm = w & 1, wn = w >> 1;
  const int m0 = blockIdx.y * 128, n0 = blockIdx.x * 128;

  floatx4 acc[4][4];
  #pragma unroll
  for (int mt = 0; mt < 4; ++mt)
    #pragma unroll
    for (int nt = 0; nt < 4; ++nt) acc[mt][nt] = (floatx4)0.f;

  for (int kt = 0; kt < KD; kt += 32) {
    #pragma unroll
    for (int i = 0; i < 2; ++i) {
      int u = tid + i * 256;               // 512 uint4 units per operand
      int row = u >> 2, g = u & 3;
      size_t offA = (size_t)(m0 + row) * KD + kt + g * 8;
      size_t offB = (size_t)(n0 + row) * KD + kt + g * 8;
      *(uint4*)&As[0][row][g*8] = *(const uint4*)(Ah + offA);
      *(uint4*)&As[1][row][g*8] = *(const uint4*)(Al + offA);
      *(uint4*)&Bs[0][row][g*8] = *(const uint4*)(Bh + offB);
      *(uint4*)&Bs[1][row][g*8] = *(const uint4*)(Bl + offB);
    }
    __syncthreads();
    half8 afh[4], afl[4], bfh[4], bfl[4];
    #pragma unroll
    for (int mt = 0; mt < 4; ++mt) {
      afh[mt] = *(const half8*)&As[0][wm*64 + mt*16 + Ln][Lq*8];
      afl[mt] = *(const half8*)&As[1][wm*64 + mt*16 + Ln][Lq*8];
    }
    #pragma unroll
    for (int nt = 0; nt < 4; ++nt) {
      bfh[nt] = *(const half8*)&Bs[0][wn*64 + nt*16 + Ln][Lq*8];
      bfl[nt] = *(const half8*)&Bs[1][wn*64 + nt*16 + Ln][Lq*8];
    }
    #pragma unroll
    for (int mt = 0; mt < 4; ++mt)
      #pragma unroll
      for (int nt = 0; nt < 4; ++nt) {
        acc[mt][nt] = __builtin_amdgcn_mfma_f32_16x16x32_f16(afh[mt], bfh[nt], acc[mt][nt], 0, 0, 0);
        acc[mt][nt] = __builtin_amdgcn_mfma_f32_16x16x32_f16(afh[mt], bfl[nt], acc[mt][nt], 0, 0, 0);
        acc[mt][nt] = __builtin_amdgcn_mfma_f32_16x16x32_f16(afl[mt], bfh[nt], acc[mt][nt], 0, 0, 0);
      }
    __syncthreads();
  }
  #pragma unroll
  for (int mt = 0; mt < 4; ++mt)
    #pragma unroll
    for (int nt = 0; nt < 4; ++nt)
      #pragma unroll
      for (int r = 0; r < 4; ++r) {
        size_t row = m0 + wm*64 + mt*16 + Lq*4 + r;
        int col = n0 + wn*64 + nt*16 + Ln;
        C[row * N + col] = acc[mt][nt][r];
      }
}

// ---------------- causal flash attention, bf16 MFMA, 8-wave blocks ----------
// Block ib runs q-tile (15-ib) then q-tile ib sequentially: 34 tile-steps per
// block (balanced). 512 threads: wave w owns a 16-row strip of the 128-row
// q-tile -> 16 waves/CU for latency hiding, same KV traffic as 4-wave version.
// K/V double-buffered through registers: one barrier per step.
__global__ __launch_bounds__(512, 4)
void flash_mfma(const float* __restrict__ qf, const unsigned short* __restrict__ kv,
                unsigned short* __restrict__ y) {
  __shared__ __align__(16) unsigned short Ks[2][64 * 64];   // [buf][key][d] swizzled
  __shared__ __align__(16) unsigned short Vt[2][64 * 64];   // [buf][d][key] swizzled
  __shared__ __align__(16) unsigned short Ps[8][16 * 64];   // per-wave [qrow][key]
  const int ib = blockIdx.x;                 // 0..7
  const int bh = blockIdx.y;
  const int b = bh >> 4, h = bh & 15;
  const int tid = threadIdx.x;
  const int w = tid >> 6, L = tid & 63;
  const int Ln = L & 15, Lq = L >> 4;
  const size_t base = (size_t)b * Tseq;
  const int hof = h * 64;

  for (int t = 0; t < 2; ++t) {
    const int qt = t ? ib : 15 - ib;
    const int q0 = qt * 128;
    const int nkt = 2 * qt + 2;

    // Q A-fragment (16-row strip), fp32 global -> bf16 regs
    short8 qfr[2];
    {
      const float* qp = qf + (base + q0 + w*16 + Ln) * Ed + hof;
      #pragma unroll
      for (int kc = 0; kc < 2; ++kc) {
        float v[8];
        *(float4*)&v[0] = *(const float4*)(qp + kc*32 + Lq*8);
        *(float4*)&v[4] = *(const float4*)(qp + kc*32 + Lq*8 + 4);
        short8 tt;
        #pragma unroll
        for (int j = 0; j < 8; ++j) tt[j] = (short)f2bf(v[j]);
        qfr[kc] = tt;
      }
    }

    float m_i[4], l_i[4];
    floatx4 O[4];
    #pragma unroll
    for (int r = 0; r < 4; ++r) { m_i[r] = -3.0e38f; l_i[r] = 0.f; }
    #pragma unroll
    for (int nt = 0; nt < 4; ++nt) O[nt] = (floatx4)0.f;

    // prologue: stage kt=0 into buffer 0 (512 uint4 units per operand)
    {
      int c = tid >> 3, g = tid & 7;
      const unsigned short* kvp = kv + (base + c) * 2048 + hof + g * 8;
      uint4 k4 = *(const uint4*)kvp;
      *(uint4*)&Ks[0][c*64 + ((g ^ (c & 7)) << 3)] = k4;
      unsigned short vv[8];
      *(uint4*)vv = *(const uint4*)(kvp + 1024);
      #pragma unroll
      for (int j = 0; j < 8; ++j) Vt[0][swz(g*8 + j, c)] = vv[j];
    }
    __syncthreads();

    int cur = 0;
    for (int kt = 0; kt < nkt; ++kt) {
      // ---- issue global loads for next tile (overlap with compute) ----
      uint4 kreg, vreg;
      const bool pre = (kt + 1 < nkt);
      const int c = tid >> 3, g = tid & 7;
      if (pre) {
        const unsigned short* kvp = kv + (base + (kt+1)*64 + c) * 2048 + hof + g * 8;
        kreg = *(const uint4*)kvp;
        vreg = *(const uint4*)(kvp + 1024);
      }

      // ---- S = Q K^T ----
      short8 kb[4][2];
      #pragma unroll
      for (int nt = 0; nt < 4; ++nt) {
        int krow = nt*16 + Ln;
        #pragma unroll
        for (int kc = 0; kc < 2; ++kc)
          kb[nt][kc] = *(const short8*)&Ks[cur][krow*64 + ((((kc*4 + Lq) ^ (krow & 7)) << 3))];
      }
      floatx4 S[4];
      #pragma unroll
      for (int nt = 0; nt < 4; ++nt) {
        floatx4 a = (floatx4)0.f;
        a = __builtin_amdgcn_mfma_f32_16x16x32_bf16(qfr[0], kb[nt][0], a, 0, 0, 0);
        a = __builtin_amdgcn_mfma_f32_16x16x32_bf16(qfr[1], kb[nt][1], a, 0, 0, 0);
        S[nt] = a;
      }
      #pragma unroll
      for (int nt = 0; nt < 4; ++nt)
        #pragma unroll
        for (int r = 0; r < 4; ++r) S[nt][r] *= 0.125f;
      if (kt >= 2*qt) {
        int rowg = q0 + w*16 + Lq*4;
        #pragma unroll
        for (int nt = 0; nt < 4; ++nt) {
          int colg = kt*64 + nt*16 + Ln;
          #pragma unroll
          for (int r = 0; r < 4; ++r)
            if (colg > rowg + r) S[nt][r] = -3.0e38f;
        }
      }

      // ---- online softmax ----
      #pragma unroll
      for (int r = 0; r < 4; ++r) {
        float mx = fmaxf(fmaxf(S[0][r], S[1][r]), fmaxf(S[2][r], S[3][r]));
        mx = fmaxf(mx, __shfl_xor(mx, 1));
        mx = fmaxf(mx, __shfl_xor(mx, 2));
        mx = fmaxf(mx, __shfl_xor(mx, 4));
        mx = fmaxf(mx, __shfl_xor(mx, 8));
        float mnew = fmaxf(m_i[r], mx);
        float alpha = __expf(m_i[r] - mnew);
        m_i[r] = mnew;
        float rs = 0.f;
        #pragma unroll
        for (int nt = 0; nt < 4; ++nt) {
          float p = __expf(S[nt][r] - mnew);
          S[nt][r] = p;
          rs += p;
        }
        rs += __shfl_xor(rs, 1);
        rs += __shfl_xor(rs, 2);
        rs += __shfl_xor(rs, 4);
        rs += __shfl_xor(rs, 8);
        l_i[r] = l_i[r] * alpha + rs;
        #pragma unroll
        for (int nt = 0; nt < 4; ++nt) O[nt][r] *= alpha;
        int prow = Lq*4 + r;
        #pragma unroll
        for (int nt = 0; nt < 4; ++nt)
          Ps[w][swz(prow, nt*16 + Ln)] = f2bf(S[nt][r]);
      }

      // ---- O += P V ----
      short8 vb[4][2], pf[2];
      #pragma unroll
      for (int nt = 0; nt < 4; ++nt) {
        int vrow = nt*16 + Ln;
        #pragma unroll
        for (int kc = 0; kc < 2; ++kc)
          vb[nt][kc] = *(const short8*)&Vt[cur][vrow*64 + ((((kc*4 + Lq) ^ (vrow & 7)) << 3))];
      }
      {
        int prow = Ln;
        #pragma unroll
        for (int kc = 0; kc < 2; ++kc)
          pf[kc] = *(const short8*)&Ps[w][prow*64 + ((((kc*4 + Lq) ^ (prow & 7)) << 3))];
      }
      #pragma unroll
      for (int nt = 0; nt < 4; ++nt) {
        O[nt] = __builtin_amdgcn_mfma_f32_16x16x32_bf16(pf[0], vb[nt][0], O[nt], 0, 0, 0);
        O[nt] = __builtin_amdgcn_mfma_f32_16x16x32_bf16(pf[1], vb[nt][1], O[nt], 0, 0, 0);
      }

      // ---- write prefetched tile into the other buffer ----
      if (pre) {
        *(uint4*)&Ks[cur^1][c*64 + ((g ^ (c & 7)) << 3)] = kreg;
        unsigned short vv[8];
        *(uint4*)vv = vreg;
        #pragma unroll
        for (int j = 0; j < 8; ++j) Vt[cur^1][swz(g*8 + j, c)] = vv[j];
      }
      __syncthreads();
      cur ^= 1;
    }

    // epilogue -> y bf16
    #pragma unroll
    for (int r = 0; r < 4; ++r) {
      float inv = 1.f / l_i[r];
      size_t rb = (base + q0 + w*16 + Lq*4 + r) * Ed + hof;
      #pragma unroll
      for (int nt = 0; nt < 4; ++nt)
        y[rb + nt*16 + Ln] = f2bf(O[nt][r] * inv);
    }
    // tile-1 prologue writes buffer 0; last reads (buffer 1) were fenced by
    // the k-loop's final __syncthreads, so no extra barrier needed here
  }
}

// ---------------- mem attention (K=3, scale 4096) + gated fusion ------------
__global__ __launch_bounds__(256)
void mem_gate(const float* __restrict__ qf, const float* __restrict__ mem_k,
              const float* __restrict__ mem_v, const float* __restrict__ gate,
              unsigned short* __restrict__ y) {
  const int tid = threadIdx.x;
  const int lane = tid & 63;
  const int g = (blockIdx.x << 2) | (tid >> 6);
  const int h = g & 15;
  const int bt = g >> 4;
  const float q = qf[(size_t)bt * Ed + h*64 + lane];
  const size_t mb = ((size_t)bt * 3) * Ed + h*64 + lane;

  float s[3];
  #pragma unroll
  for (int k = 0; k < 3; ++k) {
    float p = q * mem_k[mb + (size_t)k * Ed];
    p += __shfl_xor(p, 1);  p += __shfl_xor(p, 2);  p += __shfl_xor(p, 4);
    p += __shfl_xor(p, 8);  p += __shfl_xor(p, 16); p += __shfl_xor(p, 32);
    s[k] = p * 4096.0f;
  }
  float mx = fmaxf(s[0], fmaxf(s[1], s[2]));
  float w0 = __expf(s[0] - mx), w1 = __expf(s[1] - mx), w2 = __expf(s[2] - mx);
  float inv = 1.f / (w0 + w1 + w2);
  float ov = (w0 * mem_v[mb] + w1 * mem_v[mb + Ed] + w2 * mem_v[mb + 2*Ed]) * inv;
  float gb = gate[h];
  unsigned short* yp = y + (size_t)bt * Ed + h*64 + lane;
  float yv = bf2f(*yp);
  *yp = f2bf(ov * gb + yv * (1.f - gb));
}

extern "C" void kernel_launch(void* const* d_in, const int* in_sizes, int n_in,
                              void* d_out, int out_size, void* d_ws, size_t ws_size,
                              hipStream_t stream) {
  const float* x      = (const float*)d_in[0];
  const float* mem_k  = (const float*)d_in[1];
  const float* mem_v  = (const float*)d_in[2];
  const float* W_attn = (const float*)d_in[3];
  const float* W_proj = (const float*)d_in[4];
  const float* gate   = (const float*)d_in[5];
  float* out = (float*)d_out;

  // workspace layout (~107 MB)
  float* qf32          = (float*)d_ws;                       // [M,1024] f32
  unsigned short* kvb  = (unsigned short*)(qf32 + (size_t)MROWS*Ed);  // [M,2048] bf16
  unsigned short* ybf  = kvb + (size_t)MROWS*2048;           // [M,1024] bf16
  unsigned short* xb   = ybf + (size_t)MROWS*Ed;             // [M,1024] bf16
  unsigned short* wkv  = xb  + (size_t)MROWS*Ed;             // [2048,1024] bf16
  unsigned short* wp   = wkv + (size_t)2048*Ed;              // [1024,1024] bf16
  // scratch aliases (dead before their region's real use):
  //  - xh/xl (fp16 split of x) live only until gemm_f16x3; park them in d_out
  //    (out is written only by the final projection GEMM).
  //  - wqh/wql (fp16 split of W_attn[:, :1024]^T) live only until gemm_f16x3;
  //    park them in kvb (kv GEMM writes kvb after q is done).
  unsigned short* xh  = (unsigned short*)d_out;              // [M,1024] f16
  unsigned short* xl  = xh + (size_t)MROWS*Ed;               // [M,1024] f16
  unsigned short* wqh = kvb;                                 // [1024,1024] f16
  unsigned short* wql = wqh + (size_t)Ed*Ed;                 // [1024,1024] f16

  // 0) casts / transposes / splits
  cast_split_k<<<(MROWS*Ed/4 + 255)/256, 256, 0, stream>>>(x, xb, xh, xl, MROWS*Ed/4);
  transpose_split<<<dim3(Ed/64, Ed/64), 256, 0, stream>>>(W_attn, E3, 0, wqh, wql, Ed);
  transpose_cast<<<dim3(2048/64, Ed/64), 256, 0, stream>>>(W_attn, E3, Ed, wkv, Ed);
  transpose_cast<<<dim3(Ed/64, Ed/64), 256, 0, stream>>>(W_proj, Ed, 0, wp, Ed);
  // 1) q = x @ W_attn[:, :1024] via fp16 hi/lo 3-product MFMA (fp32-accurate)
  gemm_f16x3<Ed, Ed>
      <<<dim3(Ed/128, MROWS/128), 256, 0, stream>>>(xh, xl, wqh, wql, qf32);
  // 2) kv = xb @ wkv^T  (bf16 MFMA, bf16 out; overwrites wqh/wql scratch)
  gemm_bf16<2048, Ed, true>
      <<<dim3(2048/128, MROWS/128), 256, 0, stream>>>(xb, wkv, kvb);
  // 3) y = causal SDPA (8-wave blocks, sequential paired q-tiles)
  flash_mfma<<<dim3(8, Bsz*Hh), 512, 0, stream>>>(qf32, kvb, ybf);
  // 4) y = gate*memattn + (1-gate)*y  (in place, bf16)
  mem_gate<<<(MROWS*Hh)/4, 256, 0, stream>>>(qf32, mem_k, mem_v, gate, ybf);
  // 5) out = y @ wp^T  (bf16 MFMA, fp32 out; xh/xl scratch dead by now)
  gemm_bf16<Ed, Ed, false>
      <<<dim3(Ed/128, MROWS/128), 256, 0, stream>>>(ybf, wp, out);
}